// Round 1
// baseline (582.576 us; speedup 1.0000x reference)
//
#include <hip/hip_runtime.h>
#include <stdint.h>

typedef unsigned short u16;
typedef short bf16x8 __attribute__((ext_vector_type(8)));
typedef float f32x4 __attribute__((ext_vector_type(4)));
typedef u16 u16x8 __attribute__((ext_vector_type(8)));
typedef u16 u16x4 __attribute__((ext_vector_type(4)));

#define NHEADS 8
#define SEQ 1024
#define DM 512
#define DEPTH 64
#define BATCH 8
#define PSTRIDE 1032   // 1024 + 8 bf16 pad -> +16B per row -> bank shift of 4

__device__ __forceinline__ u16 f2bf(float f) {
    union { float f; unsigned u; } v; v.f = f;
    unsigned r = v.u + 0x7FFF + ((v.u >> 16) & 1);
    return (u16)(r >> 16);
}

// ---------------------------------------------------------------- prep
// W f32 [512][512] -> WT bf16 [512][512]; 4 matrices via blockIdx.z
__global__ void __launch_bounds__(256) transpose512(
    const float* __restrict__ w0, const float* __restrict__ w1,
    const float* __restrict__ w2, const float* __restrict__ w3,
    u16* __restrict__ wt)
{
    __shared__ float tile[32][33];
    const float* w = (blockIdx.z == 0) ? w0 : (blockIdx.z == 1) ? w1
                   : (blockIdx.z == 2) ? w2 : w3;
    u16* o = wt + (size_t)blockIdx.z * (DM * DM);
    int rb = blockIdx.y * 32, cb = blockIdx.x * 32;
    int tx = threadIdx.x, ty = threadIdx.y;  // 32 x 8
    #pragma unroll
    for (int k = 0; k < 32; k += 8)
        tile[ty + k][tx] = w[(size_t)(rb + ty + k) * DM + cb + tx];
    __syncthreads();
    #pragma unroll
    for (int k = 0; k < 32; k += 8)
        o[(size_t)(cb + ty + k) * DM + rb + tx] = f2bf(tile[tx][ty + k]);
}

// f32 -> bf16 for the three activation inputs
__global__ void __launch_bounds__(256) conv_bf16(
    const float* __restrict__ q, const float* __restrict__ k,
    const float* __restrict__ v,
    u16* __restrict__ oq, u16* __restrict__ ok, u16* __restrict__ ov)
{
    const float* src = (blockIdx.z == 0) ? q : (blockIdx.z == 1) ? k : v;
    u16* dst = (blockIdx.z == 0) ? oq : (blockIdx.z == 1) ? ok : ov;
    size_t i = ((size_t)blockIdx.x * 256 + threadIdx.x) * 8;
    f32x4 a = *(const f32x4*)(src + i);
    f32x4 b = *(const f32x4*)(src + i + 4);
    u16x8 o;
    #pragma unroll
    for (int j = 0; j < 4; j++) { o[j] = f2bf(a[j]); o[j + 4] = f2bf(b[j]); }
    *(u16x8*)(dst + i) = o;
}

// ---------------------------------------------------------------- GEMM core
// C[8192][512] = A[8192][512] @ W[512][512] + bias, W as WT[n][k], all bf16 in.
// Block tile 128x128, 4 waves 2x2, wave = 64x64 (4x4 frags), 16 MFMA / 8 loads.
// LAYOUT 0: out bf16 [B,H,S,D]; LAYOUT 1: out bf16 [B,H,D,S] via swapped
// operands (computes C^T tile so stores are s-contiguous); LAYOUT 2: f32 [M][N]
template <int LAYOUT>
__device__ __forceinline__ void gemm_tile(
    const u16* __restrict__ A, const u16* __restrict__ wt,
    const float* __restrict__ bias, void* __restrict__ out_)
{
    const int tid = threadIdx.x;
    const int wid = tid >> 6, lane = tid & 63;
    const int wm = wid >> 1, wn = wid & 1;
    const int mb = blockIdx.y * 128 + wm * 64;
    const int nb = blockIdx.x * 128 + wn * 64;
    const int lr = lane & 15, g = lane >> 4, lk = g * 8;

    f32x4 acc[4][4];
    #pragma unroll
    for (int i = 0; i < 4; i++)
        #pragma unroll
        for (int j = 0; j < 4; j++) acc[i][j] = (f32x4)0.f;

    for (int ks = 0; ks < DM; ks += 32) {
        bf16x8 a[4], bf[4];
        #pragma unroll
        for (int mt = 0; mt < 4; mt++)
            a[mt] = *(const bf16x8*)(A + (size_t)(mb + mt * 16 + lr) * DM + ks + lk);
        #pragma unroll
        for (int nt = 0; nt < 4; nt++)
            bf[nt] = *(const bf16x8*)(wt + (size_t)(nb + nt * 16 + lr) * DM + ks + lk);
        #pragma unroll
        for (int mt = 0; mt < 4; mt++)
            #pragma unroll
            for (int nt = 0; nt < 4; nt++) {
                if (LAYOUT == 1)
                    acc[mt][nt] = __builtin_amdgcn_mfma_f32_16x16x32_bf16(
                        bf[nt], a[mt], acc[mt][nt], 0, 0, 0);
                else
                    acc[mt][nt] = __builtin_amdgcn_mfma_f32_16x16x32_bf16(
                        a[mt], bf[nt], acc[mt][nt], 0, 0, 0);
            }
    }

    #pragma unroll
    for (int mt = 0; mt < 4; mt++) {
        #pragma unroll
        for (int nt = 0; nt < 4; nt++) {
            #pragma unroll
            for (int r = 0; r < 4; r++) {
                if (LAYOUT == 1) {
                    // C^T tile: col = m(s)-index = lr, row = n(d)-index
                    int m = mb + mt * 16 + lr;
                    int n = nb + nt * 16 + 4 * g + r;
                    float val = acc[mt][nt][r] + bias[n];
                    int b_ = m >> 10, s = m & 1023, h = n >> 6, d = n & 63;
                    ((u16*)out_)[((size_t)((b_ * NHEADS + h) << 6) + d) * SEQ + s] = f2bf(val);
                } else {
                    int n = nb + nt * 16 + lr;
                    int m = mb + mt * 16 + 4 * g + r;
                    float val = acc[mt][nt][r] + bias[n];
                    if (LAYOUT == 2) {
                        ((float*)out_)[(size_t)m * DM + n] = val;
                    } else {
                        int b_ = m >> 10, s = m & 1023, h = n >> 6, d = n & 63;
                        ((u16*)out_)[(((size_t)(b_ * NHEADS + h) * SEQ + s) << 6) + d] = f2bf(val);
                    }
                }
            }
        }
    }
}

__global__ void __launch_bounds__(256) qkv_proj(
    const u16* __restrict__ qbf, const u16* __restrict__ kbf,
    const u16* __restrict__ vbf, const u16* __restrict__ wt_base,
    const float* __restrict__ bq, const float* __restrict__ bk,
    const float* __restrict__ bv,
    u16* __restrict__ Qb, u16* __restrict__ Kb, u16* __restrict__ VTb)
{
    int z = blockIdx.z;
    if (z == 0)      gemm_tile<0>(qbf, wt_base,               bq, Qb);
    else if (z == 1) gemm_tile<0>(kbf, wt_base + DM * DM,     bk, Kb);
    else             gemm_tile<1>(vbf, wt_base + 2 * DM * DM, bv, VTb);
}

__global__ void __launch_bounds__(256) out_proj(
    const u16* __restrict__ X, const u16* __restrict__ wto,
    const float* __restrict__ bo, float* __restrict__ out)
{
    gemm_tile<2>(X, wto, bo, out);
}

// ---------------------------------------------------------------- attention
// One block per (h, 16-row q-tile, b); 256 threads = 4 waves, wave owns 256
// K-columns. SWAPPED-OPERAND QK^T: acc = mfma(K_frag, Q_frag) so each lane
// holds S[q = lane&15][k = wbase + nt*16 + 4g + r] -> 4 CONSECUTIVE k per acc.
// Epilogue then uses f32x4 addw loads, f32x4 attn stores, b64 P-stash
// (was 64 scalar each). blockIdx remap co-locates the 8 h-blocks sharing
// one (b,qt) addw panel on the same XCD (id%8 invariant per group).
__global__ void __launch_bounds__(256) attn_kernel(
    const u16* __restrict__ Q, const u16* __restrict__ K,
    const u16* __restrict__ VT, const float* __restrict__ mask,
    const float* __restrict__ addw, float* __restrict__ attn_out,
    u16* __restrict__ X)
{
    __shared__ u16 Pl[16 * PSTRIDE];
    __shared__ float redm[4][16];
    __shared__ float reds[4][16];

    // bijective remap: id = c + 8*(h + 8*u), p = 8u + c = b*64+qt
    // -> all 8 h-blocks of one (b,qt) have identical id%8 -> same XCD.
    const int id = blockIdx.x;
    const int c = id & 7, t = id >> 3;
    const int h = t & 7;
    const int p = ((t >> 3) << 3) | c;
    const int qt = p & 63, b = p >> 6;

    const int tid = threadIdx.x, wid = tid >> 6, lane = tid & 63;
    const int lr = lane & 15, g = lane >> 4, lk = g * 8;
    const size_t head = (size_t)(b * NHEADS + h) * (SEQ * DEPTH);
    const u16* Qh = Q + head + (size_t)qt * 16 * DEPTH;
    const u16* Kh = K + head;
    const u16* Vh = VT + head;  // [64][1024] bf16
    const int wbase = wid << 8;  // wave's k-column base

    // ---- phase 1: S (transposed acc) = K @ Q^T
    bf16x8 qf0 = *(const bf16x8*)(Qh + lr * DEPTH + lk);
    bf16x8 qf1 = *(const bf16x8*)(Qh + lr * DEPTH + 32 + lk);
    f32x4 acc[16];
    #pragma unroll
    for (int nt = 0; nt < 16; nt++) acc[nt] = (f32x4)0.f;
    #pragma unroll
    for (int nt = 0; nt < 16; nt++) {
        const u16* kp = Kh + (size_t)(wbase + (nt << 4) + lr) * DEPTH + lk;
        bf16x8 k0 = *(const bf16x8*)kp;
        bf16x8 k1 = *(const bf16x8*)(kp + 32);
        acc[nt] = __builtin_amdgcn_mfma_f32_16x16x32_bf16(k0, qf0, acc[nt], 0, 0, 0);
        acc[nt] = __builtin_amdgcn_mfma_f32_16x16x32_bf16(k1, qf1, acc[nt], 0, 0, 0);
    }

    // ---- scale + mask + per-lane max over the 64 k-values this lane holds
    const float* mrow = mask + ((size_t)b << 10);
    float mx = -3.0e38f;
    #pragma unroll
    for (int nt = 0; nt < 16; nt++) {
        f32x4 mr = *(const f32x4*)(mrow + wbase + (nt << 4) + 4 * g);
        #pragma unroll
        for (int r = 0; r < 4; r++) {
            acc[nt][r] = acc[nt][r] * 0.125f + mr[r] * -1e9f;
            mx = fmaxf(mx, acc[nt][r]);
        }
    }
    // rows live on lane&15; combine the 4 g-groups, then the 4 waves
    mx = fmaxf(mx, __shfl_xor(mx, 16, 64));
    mx = fmaxf(mx, __shfl_xor(mx, 32, 64));
    if (lane < 16) redm[wid][lr] = mx;
    __syncthreads();
    float gm = fmaxf(fmaxf(redm[0][lr], redm[1][lr]),
                     fmaxf(redm[2][lr], redm[3][lr]));

    // ---- exp + row sum
    float sm = 0.f;
    #pragma unroll
    for (int nt = 0; nt < 16; nt++)
        #pragma unroll
        for (int r = 0; r < 4; r++) {
            float pv = __expf(acc[nt][r] - gm);
            acc[nt][r] = pv;
            sm += pv;
        }
    sm += __shfl_xor(sm, 16, 64);
    sm += __shfl_xor(sm, 32, 64);
    if (lane < 16) reds[wid][lr] = sm;
    __syncthreads();
    float iv = 1.0f / (reds[0][lr] + reds[1][lr] + reds[2][lr] + reds[3][lr]);

    // ---- phase 2: scale by 1/sum * addw, vectorized stores + P stash
    const int qglob = (qt << 4) + lr;
    const size_t awbase = ((size_t)((b << 10) + qglob)) << 10;
    const size_t aobase = ((size_t)(((b * NHEADS + h) << 10) + qglob)) << 10;
    #pragma unroll
    for (int nt = 0; nt < 16; nt++) {
        int k0 = wbase + (nt << 4) + 4 * g;
        f32x4 aw = *(const f32x4*)(addw + awbase + k0);
        f32x4 o;
        u16x4 pb;
        #pragma unroll
        for (int r = 0; r < 4; r++) {
            float v = acc[nt][r] * iv * aw[r];
            o[r] = v;
            pb[r] = f2bf(v);
        }
        *(f32x4*)(attn_out + aobase + k0) = o;
        *(u16x4*)(Pl + lr * PSTRIDE + k0) = pb;
    }
    __syncthreads();

    // ---- phase 3: X = P @ V; wave wid handles d in [wid*16, wid*16+16)
    f32x4 x = (f32x4)0.f;
    const u16* vrow = Vh + (size_t)((wid << 4) + lr) * SEQ;
    for (int ks = 0; ks < SEQ; ks += 32) {
        bf16x8 a = *(const bf16x8*)(Pl + lr * PSTRIDE + ks + lk);
        bf16x8 bv = *(const bf16x8*)(vrow + ks + lk);
        x = __builtin_amdgcn_mfma_f32_16x16x32_bf16(a, bv, x, 0, 0, 0);
    }
    int d = (h << 6) + (wid << 4) + lr;
    #pragma unroll
    for (int r = 0; r < 4; r++)
        X[((size_t)((b << 10) + (qt << 4) + 4 * g + r)) * DM + d] = f2bf(x[r]);
}

// ---------------------------------------------------------------- launch
extern "C" void kernel_launch(void* const* d_in, const int* in_sizes, int n_in,
                              void* d_out, int out_size, void* d_ws, size_t ws_size,
                              hipStream_t stream)
{
    const float* q_in = (const float*)d_in[0];
    const float* k_in = (const float*)d_in[1];
    const float* v_in = (const float*)d_in[2];
    const float* mask = (const float*)d_in[3];
    const float* addw = (const float*)d_in[4];
    const float* wq = (const float*)d_in[5];
    const float* bq = (const float*)d_in[6];
    const float* wk = (const float*)d_in[7];
    const float* bk = (const float*)d_in[8];
    const float* wv = (const float*)d_in[9];
    const float* bv = (const float*)d_in[10];
    const float* wo = (const float*)d_in[11];
    const float* bo = (const float*)d_in[12];

    const size_t ACT = (size_t)BATCH * SEQ * DM;   // 4,194,304 elements

    // workspace: 34 MB total
    u16* ws = (u16*)d_ws;
    u16* wt  = ws;                    // 4 * 512*512 bf16      (2 MB)
    u16* Qb  = wt + 4 * DM * DM;      // [B,H,S,D] bf16        (8 MB)
    u16* Kb  = Qb + ACT;              // [B,H,S,D] bf16        (8 MB)
    u16* VTb = Kb + ACT;              // [B,H,D,S] bf16        (8 MB)
    u16* Xb  = VTb + ACT;             // [B,S,DM]  bf16        (8 MB)

    float* out0 = (float*)d_out;                         // [B,S,512] f32
    float* attn_out = out0 + ACT;                        // [B,H,S,S] f32 (268 MB)

    // bf16-converted activations live in the attn_out region of d_out:
    // written by conv_bf16, consumed by qkv_proj, then fully overwritten by
    // attn_kernel's attn output. 24 MB << 268 MB.
    u16* qbf = (u16*)attn_out;
    u16* kbf = qbf + ACT;
    u16* vbf = kbf + ACT;

    transpose512<<<dim3(16, 16, 4), dim3(32, 8), 0, stream>>>(wq, wk, wv, wo, wt);
    conv_bf16<<<dim3(2048, 1, 3), 256, 0, stream>>>(q_in, k_in, v_in, qbf, kbf, vbf);
    qkv_proj<<<dim3(4, 64, 3), 256, 0, stream>>>(qbf, kbf, vbf, wt, bq, bk, bv,
                                                 Qb, Kb, VTb);
    attn_kernel<<<dim3(4096), 256, 0, stream>>>(Qb, Kb, VTb, mask, addw,
                                                attn_out, Xb);
    out_proj<<<dim3(4, 64, 1), 256, 0, stream>>>(Xb, wt + 3 * DM * DM, bo, out0);
}